// Round 8
// baseline (1201.528 us; speedup 1.0000x reference)
//
#include <hip/hip_runtime.h>

// LSTM B=512,T=512,D=128,H=64,O=1. Gate order i,f,g,o.
// K1: pre[b][t][g] = x[b,t,:]@Wih0^T + bih0+bhh0  (fp32 register-tiled GEMM).
// K2: fused 2-layer recurrence, 512 blocks (1 batch) x 512 thr, launch_bounds(512,1).
//   Lesson R3/R4/R6: any layout needing >128 VGPRs at >=2 blocks/CU gets silently
//   demoted (R6: VGPR=128 vs 250 declared, 4x VALU bloat). Fix: 96 weight
//   floats/thread (the 49152/512 floor) + (512,1) honest allocation; 1 block/CU,
//   512 blocks run as 2 throughput-equivalent passes.
//   Thread group = 16 lanes owning 2 hidden units, all 64 k split 16x4.
//   16 chains/thread: (2 units x 4 gates x 2 layers), layers SKEWED one step
//   -> single barrier/iter. Cross-lane reduce: DPP ror8 (u-bit, select-free via
//   weight permutation u = s3^l3), quad_perm xor2 (layer select), ds_swizzle
//   xor4 + quad_perm xor1 butterflies. All 4 gates of (unit,layer) land in one
//   lane -> cell update fully in-register.
// ws: 512*512*256*4 = 256 MiB fp32 pre buffer (read-only in K2).

#define TSTEPS 512

__device__ __forceinline__ float sigf(float x){ return 1.0f/(1.0f+__expf(-x)); }
__device__ __forceinline__ float tanh_fast(float x){
  float ax=fabsf(x); float e=__expf(-2.0f*ax); float r=(1.0f-e)/(1.0f+e); return copysignf(r,x);
}
// a + dpp_shuffle(b); CTRL: 0xB1=quad xor1, 0x4E=quad xor2, 0x128=row_ror:8 (=xor8 in 16)
template<int CTRL>
__device__ __forceinline__ float add_dpp(float a, float b){
  return a + __int_as_float(__builtin_amdgcn_update_dpp(
      0, __float_as_int(b), CTRL, 0xF, 0xF, true));
}
__device__ __forceinline__ float swz_xor4(float v){
  return __int_as_float(__builtin_amdgcn_ds_swizzle(__float_as_int(v), 0x101F)); // lane^4
}
__device__ __forceinline__ float dot4f(const float* w, float4 h, float acc){
  acc = fmaf(w[0], h.x, acc); acc = fmaf(w[1], h.y, acc);
  acc = fmaf(w[2], h.z, acc); acc = fmaf(w[3], h.w, acc);
  return acc;
}

// ---------------- K1: input projection GEMM (fp32 VALU) ----------------
__global__ __launch_bounds__(256) void k_inproj(
    const float* __restrict__ x, const float* __restrict__ W,
    const float* __restrict__ bih, const float* __restrict__ bhh,
    float* __restrict__ pre)
{
    __shared__ float xs[64][128];
    const int tid = threadIdx.x;
    const long row0 = (long)blockIdx.x * 64;

    const float4* __restrict__ xv = (const float4*)(x + row0 * 128);
    float4* xsv = (float4*)(&xs[0][0]);
#pragma unroll
    for (int i = 0; i < 8; ++i) xsv[tid + 256 * i] = xv[tid + 256 * i];
    __syncthreads();

    const int tx = tid & 63;
    const int ty = tid >> 6;

    float acc[16][4];
#pragma unroll
    for (int i = 0; i < 16; ++i)
#pragma unroll
        for (int j = 0; j < 4; ++j) acc[i][j] = 0.0f;

#pragma unroll 1
    for (int kc = 0; kc < 16; ++kc) {
        const int k0 = kc * 8;
        float4 w0[4], w1[4];
#pragma unroll
        for (int j = 0; j < 4; ++j) {
            const float* wr = W + (tx + 64 * j) * 128 + k0;
            w0[j] = *(const float4*)wr;
            w1[j] = *(const float4*)(wr + 4);
        }
#pragma unroll
        for (int i = 0; i < 16; ++i) {
            const int r = ty * 16 + i;
            float4 a0 = *(const float4*)(&xs[r][k0]);
            float4 a1 = *(const float4*)(&xs[r][k0 + 4]);
#pragma unroll
            for (int j = 0; j < 4; ++j) {
                float s = acc[i][j];
                s = fmaf(a0.x, w0[j].x, s); s = fmaf(a0.y, w0[j].y, s);
                s = fmaf(a0.z, w0[j].z, s); s = fmaf(a0.w, w0[j].w, s);
                s = fmaf(a1.x, w1[j].x, s); s = fmaf(a1.y, w1[j].y, s);
                s = fmaf(a1.z, w1[j].z, s); s = fmaf(a1.w, w1[j].w, s);
                acc[i][j] = s;
            }
        }
    }

    float bsum[4];
#pragma unroll
    for (int j = 0; j < 4; ++j) { const int g = tx + 64 * j; bsum[j] = bih[g] + bhh[g]; }
#pragma unroll
    for (int i = 0; i < 16; ++i) {
        const long r = row0 + ty * 16 + i;
        float* pr = pre + r * 256;
#pragma unroll
        for (int j = 0; j < 4; ++j) pr[tx + 64 * j] = acc[i][j] + bsum[j];
    }
}

// ---------------- K2: fused 2-layer recurrence + head ----------------
__global__ __launch_bounds__(512, 1) void k_fused(
    const float* __restrict__ Whh0, const float* __restrict__ Wih1,
    const float* __restrict__ Whh1,
    const float* __restrict__ bih1, const float* __restrict__ bhh1,
    const float* __restrict__ Wfc,  const float* __restrict__ bfc,
    const float* __restrict__ pre,  float* __restrict__ out)
{
    const int tid = threadIdx.x;
    const int b   = blockIdx.x;
    const int l1  = (tid >> 1) & 1;   // final layer this lane owns
    const int l3  = (tid >> 3) & 1;   // final (local) unit this lane owns
    const int kb  = (tid & 15) * 4;   // k-slice base (4 floats of 64)
    const int grp = (tid >> 4) & 31;  // 16-lane group = 2 hidden units
    const int U0  = 2 * grp + l3;     // global unit for this lane's outputs

    __shared__ __align__(16) float h0s[2][64];
    __shared__ __align__(16) float h1s[2][64];

    // ---- weights: 96 floats/thread. slot s3 stores unit (s3 ^ l3) so the
    // xor8 (ror8) merge needs no lane-dependent selects.
    float w0[2][4][4], wi[2][4][4], wh[2][4][4];
#pragma unroll
    for (int s3 = 0; s3 < 2; ++s3) {
        const int U = 2 * grp + (s3 ^ l3);
#pragma unroll
        for (int g = 0; g < 4; ++g) {
            const int row = g * 64 + U;
            float4 a = *(const float4*)(Whh0 + row * 64 + kb);
            float4 c = *(const float4*)(Wih1 + row * 64 + kb);
            float4 d = *(const float4*)(Whh1 + row * 64 + kb);
            w0[s3][g][0]=a.x; w0[s3][g][1]=a.y; w0[s3][g][2]=a.z; w0[s3][g][3]=a.w;
            wi[s3][g][0]=c.x; wi[s3][g][1]=c.y; wi[s3][g][2]=c.z; wi[s3][g][3]=c.w;
            wh[s3][g][0]=d.x; wh[s3][g][1]=d.y; wh[s3][g][2]=d.z; wh[s3][g][3]=d.w;
        }
    }
    float bias1v[4];
#pragma unroll
    for (int g = 0; g < 4; ++g) bias1v[g] = bih1[g * 64 + U0] + bhh1[g * 64 + U0];

    const float* __restrict__ pb = pre + (size_t)b * TSTEPS * 256;
    float pc[4];
#pragma unroll
    for (int g = 0; g < 4; ++g) pc[g] = pb[g * 64 + U0];   // t=0

    if (tid < 64) { h0s[0][tid] = 0.0f; h1s[0][tid] = 0.0f; }
    float cst = 0.0f;   // cell state of (U0, layer l1)
    int p = 0;
    __syncthreads();

#pragma unroll 1
    for (int n = 0; n <= TSTEPS; ++n) {
        // h slices (parity p): h0_{n-1}, h1_{n-2}
        float4 h0v = *(const float4*)&h0s[p][kb];
        float4 h1v = *(const float4*)&h1s[p][kb];

        // prefetch pre0 for t=n+1 (clamped; invalid iters guarded below)
        float pn_[4];
        const int tn = (n < TSTEPS - 1) ? (n + 1) : 0;
#pragma unroll
        for (int g = 0; g < 4; ++g) pn_[g] = pb[tn * 256 + g * 64 + U0];

        // ---- partial dots: 16 chains, k-slice of 4 ----
        float p0[2][4], p1[2][4];
#pragma unroll
        for (int s3 = 0; s3 < 2; ++s3)
#pragma unroll
            for (int g = 0; g < 4; ++g) {
                p0[s3][g] = dot4f(w0[s3][g], h0v, 0.0f);
                float s = dot4f(wi[s3][g], h0v, 0.0f);
                p1[s3][g] = dot4f(wh[s3][g], h1v, s);
            }

        // ---- reduce across 16 lanes ----
        // stage A (xor8, unit-bit, select-free by weight permutation)
        float m0[4], m1[4];
#pragma unroll
        for (int g = 0; g < 4; ++g) {
            m0[g] = add_dpp<0x128>(p0[0][g], p0[1][g]);
            m1[g] = add_dpp<0x128>(p1[0][g], p1[1][g]);
        }
        // stage B (xor2, layer-bit, cndmask select)
        float q[4];
#pragma unroll
        for (int g = 0; g < 4; ++g) {
            float xsel = l1 ? m1[g] : m0[g];
            float ysel = l1 ? m0[g] : m1[g];
            q[g] = add_dpp<0x4E>(xsel, ysel);
        }
        // stage C (xor4 butterfly via ds_swizzle), stage D (xor1 quad butterfly)
#pragma unroll
        for (int g = 0; g < 4; ++g) q[g] += swz_xor4(q[g]);
#pragma unroll
        for (int g = 0; g < 4; ++g) q[g] = add_dpp<0xB1>(q[g], q[g]);

        // ---- finalize: z, gates, cell ----
        float z0 = q[0] + (l1 ? bias1v[0] : pc[0]);
        float z1 = q[1] + (l1 ? bias1v[1] : pc[1]);
        float z2 = q[2] + (l1 ? bias1v[2] : pc[2]);
        float z3 = q[3] + (l1 ? bias1v[3] : pc[3]);
        float i_ = sigf(z0), f_ = sigf(z1), g_ = tanh_fast(z2), o_ = sigf(z3);
        const bool valid = l1 ? (n >= 1) : (n < TSTEPS);
        float h;
        if (valid) { cst = fmaf(f_, cst, i_ * g_); h = o_ * tanh_fast(cst); }
        else h = 0.0f;

        // one writer lane per (unit, layer): bits l0,l2 zero
        if ((tid & 5) == 0) {
            float* dst = l1 ? &h1s[p ^ 1][U0] : &h0s[p ^ 1][U0];
            *dst = h;
        }
        __syncthreads();
        p ^= 1;
#pragma unroll
        for (int g = 0; g < 4; ++g) pc[g] = pn_[g];
    }

    // ---- head: out[b] = h1_{T-1} . Wfc + bfc (wave 0) ----
    if (tid < 64) {
        float v = h1s[p][tid] * Wfc[tid];
#pragma unroll
        for (int off = 32; off > 0; off >>= 1) v += __shfl_down(v, off);
        if (tid == 0) out[b] = v + bfc[0];
    }
}

extern "C" void kernel_launch(void* const* d_in, const int* in_sizes, int n_in,
                              void* d_out, int out_size, void* d_ws, size_t ws_size,
                              hipStream_t stream)
{
    const float* x    = (const float*)d_in[0];
    const float* Wih0 = (const float*)d_in[1];
    const float* Whh0 = (const float*)d_in[2];
    const float* bih0 = (const float*)d_in[3];
    const float* bhh0 = (const float*)d_in[4];
    const float* Wih1 = (const float*)d_in[5];
    const float* Whh1 = (const float*)d_in[6];
    const float* bih1 = (const float*)d_in[7];
    const float* bhh1 = (const float*)d_in[8];
    const float* Wfc  = (const float*)d_in[9];
    const float* bfc  = (const float*)d_in[10];
    float* out = (float*)d_out;
    float* pre = (float*)d_ws;  // [B][T][256] fp32 = 256 MiB

    k_inproj<<<4096, 256, 0, stream>>>(x, Wih0, bih0, bhh0, pre);
    k_fused<<<512, 512, 0, stream>>>(Whh0, Wih1, Whh1, bih1, bhh1, Wfc, bfc, pre, out);
}

// Round 9
// 1198.961 us; speedup vs baseline: 1.0021x; 1.0021x over previous
//
#include <hip/hip_runtime.h>

// LSTM B=512,T=512,D=128,H=64,O=1. Gate order i,f,g,o.
// K1: pre[b][t][g] = x[b,t,:]@Wih0^T + bih0+bhh0  (fp32 register-tiled GEMM).
// K2: fused 2-layer recurrence, 512 blocks (1 batch) x 512 thr, launch_bounds(512,1).
//   Register-demotion history: R3(80/128), R4(44/48), R6(128/250 w/ pins+cap128),
//   R8(72/130 no pins, cap256). Diagnosis: backend sinks loop-invariant weight
//   loads into the loop unless (a) remat is impossible (asm pin / computed value)
//   AND (b) the VGPR cap permits residency. R5 (computed, 232 VGPR) is the
//   existence proof. This round: pins + (512,1) cap-256 — the untested cell.
//   Weights MUST be registers: each is used once/step (AI=1), so any memory
//   tier is a 196 KB/step/CU stream; only the RF has that bandwidth.
//   Thread group = 16 lanes owning 2 hidden units, all 64 k split 16x4.
//   16 chains/thread (2 units x 4 gates x 2 layers), layers SKEWED one step ->
//   one barrier/iter. Reduce: DPP ror8 (select-free via weight permutation
//   u=s3^l3), quad_perm xor2 (layer), ds_swizzle xor4, quad_perm xor1.
//   All 4 gates of (unit,layer) land in one lane -> in-register cell update.
// ws: 512*512*256*4 = 256 MiB fp32 pre buffer (read-only in K2).

#define TSTEPS 512

__device__ __forceinline__ float sigf(float x){ return 1.0f/(1.0f+__expf(-x)); }
__device__ __forceinline__ float tanh_fast(float x){
  float ax=fabsf(x); float e=__expf(-2.0f*ax); float r=(1.0f-e)/(1.0f+e); return copysignf(r,x);
}
#define KEEP(x) asm volatile("" : "+v"(x))
// a + dpp_shuffle(b); CTRL: 0xB1=quad xor1, 0x4E=quad xor2, 0x128=row_ror:8 (=xor8 in 16)
template<int CTRL>
__device__ __forceinline__ float add_dpp(float a, float b){
  return a + __int_as_float(__builtin_amdgcn_update_dpp(
      0, __float_as_int(b), CTRL, 0xF, 0xF, true));
}
__device__ __forceinline__ float swz_xor4(float v){
  return __int_as_float(__builtin_amdgcn_ds_swizzle(__float_as_int(v), 0x101F)); // lane^4
}
__device__ __forceinline__ float dot4f(const float* w, float4 h, float acc){
  acc = fmaf(w[0], h.x, acc); acc = fmaf(w[1], h.y, acc);
  acc = fmaf(w[2], h.z, acc); acc = fmaf(w[3], h.w, acc);
  return acc;
}

// ---------------- K1: input projection GEMM (fp32 VALU) ----------------
__global__ __launch_bounds__(256) void k_inproj(
    const float* __restrict__ x, const float* __restrict__ W,
    const float* __restrict__ bih, const float* __restrict__ bhh,
    float* __restrict__ pre)
{
    __shared__ float xs[64][128];
    const int tid = threadIdx.x;
    const long row0 = (long)blockIdx.x * 64;

    const float4* __restrict__ xv = (const float4*)(x + row0 * 128);
    float4* xsv = (float4*)(&xs[0][0]);
#pragma unroll
    for (int i = 0; i < 8; ++i) xsv[tid + 256 * i] = xv[tid + 256 * i];
    __syncthreads();

    const int tx = tid & 63;
    const int ty = tid >> 6;

    float acc[16][4];
#pragma unroll
    for (int i = 0; i < 16; ++i)
#pragma unroll
        for (int j = 0; j < 4; ++j) acc[i][j] = 0.0f;

#pragma unroll 1
    for (int kc = 0; kc < 16; ++kc) {
        const int k0 = kc * 8;
        float4 w0[4], w1[4];
#pragma unroll
        for (int j = 0; j < 4; ++j) {
            const float* wr = W + (tx + 64 * j) * 128 + k0;
            w0[j] = *(const float4*)wr;
            w1[j] = *(const float4*)(wr + 4);
        }
#pragma unroll
        for (int i = 0; i < 16; ++i) {
            const int r = ty * 16 + i;
            float4 a0 = *(const float4*)(&xs[r][k0]);
            float4 a1 = *(const float4*)(&xs[r][k0 + 4]);
#pragma unroll
            for (int j = 0; j < 4; ++j) {
                float s = acc[i][j];
                s = fmaf(a0.x, w0[j].x, s); s = fmaf(a0.y, w0[j].y, s);
                s = fmaf(a0.z, w0[j].z, s); s = fmaf(a0.w, w0[j].w, s);
                s = fmaf(a1.x, w1[j].x, s); s = fmaf(a1.y, w1[j].y, s);
                s = fmaf(a1.z, w1[j].z, s); s = fmaf(a1.w, w1[j].w, s);
                acc[i][j] = s;
            }
        }
    }

    float bsum[4];
#pragma unroll
    for (int j = 0; j < 4; ++j) { const int g = tx + 64 * j; bsum[j] = bih[g] + bhh[g]; }
#pragma unroll
    for (int i = 0; i < 16; ++i) {
        const long r = row0 + ty * 16 + i;
        float* pr = pre + r * 256;
#pragma unroll
        for (int j = 0; j < 4; ++j) pr[tx + 64 * j] = acc[i][j] + bsum[j];
    }
}

// ---------------- K2: fused 2-layer recurrence + head ----------------
__global__ __launch_bounds__(512, 1) void k_fused(
    const float* __restrict__ Whh0, const float* __restrict__ Wih1,
    const float* __restrict__ Whh1,
    const float* __restrict__ bih1, const float* __restrict__ bhh1,
    const float* __restrict__ Wfc,  const float* __restrict__ bfc,
    const float* __restrict__ pre,  float* __restrict__ out)
{
    const int tid = threadIdx.x;
    const int b   = blockIdx.x;
    const int l1  = (tid >> 1) & 1;   // final layer this lane owns
    const int l3  = (tid >> 3) & 1;   // final (local) unit this lane owns
    const int kb  = (tid & 15) * 4;   // k-slice base (4 floats of 64)
    const int grp = (tid >> 4) & 31;  // 16-lane group = 2 hidden units
    const int U0  = 2 * grp + l3;     // global unit for this lane's outputs

    __shared__ __align__(16) float h0s[2][64];
    __shared__ __align__(16) float h1s[2][64];

    // ---- weights: 96 floats/thread. slot s3 stores unit (s3 ^ l3) so the
    // xor8 (ror8) merge needs no lane-dependent selects.
    float w0[2][4][4], wi[2][4][4], wh[2][4][4];
#pragma unroll
    for (int s3 = 0; s3 < 2; ++s3) {
        const int U = 2 * grp + (s3 ^ l3);
#pragma unroll
        for (int g = 0; g < 4; ++g) {
            const int row = g * 64 + U;
            float4 a = *(const float4*)(Whh0 + row * 64 + kb);
            float4 c = *(const float4*)(Wih1 + row * 64 + kb);
            float4 d = *(const float4*)(Whh1 + row * 64 + kb);
            w0[s3][g][0]=a.x; w0[s3][g][1]=a.y; w0[s3][g][2]=a.z; w0[s3][g][3]=a.w;
            wi[s3][g][0]=c.x; wi[s3][g][1]=c.y; wi[s3][g][2]=c.z; wi[s3][g][3]=c.w;
            wh[s3][g][0]=d.x; wh[s3][g][1]=d.y; wh[s3][g][2]=d.z; wh[s3][g][3]=d.w;
        }
    }
    float bias1v[4];
#pragma unroll
    for (int g = 0; g < 4; ++g) bias1v[g] = bih1[g * 64 + U0] + bhh1[g * 64 + U0];

    // pin all weights+biases in VGPRs: opaque redefinition — the backend cannot
    // rematerialize them by re-loading inside the loop (R8: it did exactly that,
    // VGPR=72, +4x issue traffic). Budget: ~130 live < 256 cap at (512,1).
#pragma unroll
    for (int s3 = 0; s3 < 2; ++s3)
#pragma unroll
        for (int g = 0; g < 4; ++g)
#pragma unroll
            for (int k = 0; k < 4; ++k) {
                KEEP(w0[s3][g][k]); KEEP(wi[s3][g][k]); KEEP(wh[s3][g][k]);
            }
#pragma unroll
    for (int g = 0; g < 4; ++g) KEEP(bias1v[g]);

    const float* __restrict__ pb = pre + (size_t)b * TSTEPS * 256;
    float pc[4];
#pragma unroll
    for (int g = 0; g < 4; ++g) pc[g] = pb[g * 64 + U0];   // t=0

    if (tid < 64) { h0s[0][tid] = 0.0f; h1s[0][tid] = 0.0f; }
    float cst = 0.0f;   // cell state of (U0, layer l1)
    int p = 0;
    __syncthreads();

#pragma unroll 1
    for (int n = 0; n <= TSTEPS; ++n) {
        // h slices (parity p): h0_{n-1}, h1_{n-2}
        float4 h0v = *(const float4*)&h0s[p][kb];
        float4 h1v = *(const float4*)&h1s[p][kb];

        // prefetch pre0 for t=n+1 (clamped; invalid iters guarded below)
        float pn_[4];
        const int tn = (n < TSTEPS - 1) ? (n + 1) : 0;
#pragma unroll
        for (int g = 0; g < 4; ++g) pn_[g] = pb[tn * 256 + g * 64 + U0];

        // ---- partial dots: 16 chains, k-slice of 4 ----
        float p0[2][4], p1[2][4];
#pragma unroll
        for (int s3 = 0; s3 < 2; ++s3)
#pragma unroll
            for (int g = 0; g < 4; ++g) {
                p0[s3][g] = dot4f(w0[s3][g], h0v, 0.0f);
                float s = dot4f(wi[s3][g], h0v, 0.0f);
                p1[s3][g] = dot4f(wh[s3][g], h1v, s);
            }

        // ---- reduce across 16 lanes ----
        // stage A (xor8, unit-bit, select-free by weight permutation)
        float m0[4], m1[4];
#pragma unroll
        for (int g = 0; g < 4; ++g) {
            m0[g] = add_dpp<0x128>(p0[0][g], p0[1][g]);
            m1[g] = add_dpp<0x128>(p1[0][g], p1[1][g]);
        }
        // stage B (xor2, layer-bit, cndmask select)
        float q[4];
#pragma unroll
        for (int g = 0; g < 4; ++g) {
            float xsel = l1 ? m1[g] : m0[g];
            float ysel = l1 ? m0[g] : m1[g];
            q[g] = add_dpp<0x4E>(xsel, ysel);
        }
        // stage C (xor4 butterfly via ds_swizzle), stage D (xor1 quad butterfly)
#pragma unroll
        for (int g = 0; g < 4; ++g) q[g] += swz_xor4(q[g]);
#pragma unroll
        for (int g = 0; g < 4; ++g) q[g] = add_dpp<0xB1>(q[g], q[g]);

        // ---- finalize: z, gates, cell ----
        float z0 = q[0] + (l1 ? bias1v[0] : pc[0]);
        float z1 = q[1] + (l1 ? bias1v[1] : pc[1]);
        float z2 = q[2] + (l1 ? bias1v[2] : pc[2]);
        float z3 = q[3] + (l1 ? bias1v[3] : pc[3]);
        float i_ = sigf(z0), f_ = sigf(z1), g_ = tanh_fast(z2), o_ = sigf(z3);
        const bool valid = l1 ? (n >= 1) : (n < TSTEPS);
        float h;
        if (valid) { cst = fmaf(f_, cst, i_ * g_); h = o_ * tanh_fast(cst); }
        else h = 0.0f;

        // one writer lane per (unit, layer): bits l0,l2 zero
        if ((tid & 5) == 0) {
            float* dst = l1 ? &h1s[p ^ 1][U0] : &h0s[p ^ 1][U0];
            *dst = h;
        }
        __syncthreads();
        p ^= 1;
#pragma unroll
        for (int g = 0; g < 4; ++g) pc[g] = pn_[g];
    }

    // ---- head: out[b] = h1_{T-1} . Wfc + bfc (wave 0) ----
    if (tid < 64) {
        float v = h1s[p][tid] * Wfc[tid];
#pragma unroll
        for (int off = 32; off > 0; off >>= 1) v += __shfl_down(v, off);
        if (tid == 0) out[b] = v + bfc[0];
    }
}

extern "C" void kernel_launch(void* const* d_in, const int* in_sizes, int n_in,
                              void* d_out, int out_size, void* d_ws, size_t ws_size,
                              hipStream_t stream)
{
    const float* x    = (const float*)d_in[0];
    const float* Wih0 = (const float*)d_in[1];
    const float* Whh0 = (const float*)d_in[2];
    const float* bih0 = (const float*)d_in[3];
    const float* bhh0 = (const float*)d_in[4];
    const float* Wih1 = (const float*)d_in[5];
    const float* Whh1 = (const float*)d_in[6];
    const float* bih1 = (const float*)d_in[7];
    const float* bhh1 = (const float*)d_in[8];
    const float* Wfc  = (const float*)d_in[9];
    const float* bfc  = (const float*)d_in[10];
    float* out = (float*)d_out;
    float* pre = (float*)d_ws;  // [B][T][256] fp32 = 256 MiB

    k_inproj<<<4096, 256, 0, stream>>>(x, Wih0, bih0, bhh0, pre);
    k_fused<<<512, 512, 0, stream>>>(Whh0, Wih1, Whh1, bih1, bhh1, Wfc, bfc, pre, out);
}